// Round 1
// baseline (931.908 us; speedup 1.0000x reference)
//
#include <hip/hip_runtime.h>
#include <math.h>

#define NEG_SLOPE 0.2f

// ---------------------------------------------------------------------------
// CSR build: degree count -> exclusive scan -> scatter
// ---------------------------------------------------------------------------
__global__ void k_degree(const int* __restrict__ dstA, int E, int* __restrict__ deg) {
    int e = blockIdx.x * blockDim.x + threadIdx.x;
    if (e < E) atomicAdd(&deg[dstA[e]], 1);
}

__global__ void k_scan(const int* __restrict__ deg, int* __restrict__ row_start, int N) {
    __shared__ int sums[1024];
    int tid = threadIdx.x;
    int chunk = (N + 1023) >> 10;
    int begin = tid * chunk;
    int end = begin + chunk; if (end > N) end = N; if (begin > N) begin = N;
    int s = 0;
    for (int i = begin; i < end; ++i) s += deg[i];
    sums[tid] = s;
    __syncthreads();
    // Hillis-Steele inclusive scan over 1024 block sums
    for (int off = 1; off < 1024; off <<= 1) {
        int t = (tid >= off) ? sums[tid - off] : 0;
        __syncthreads();
        sums[tid] += t;
        __syncthreads();
    }
    int run = sums[tid] - s;  // exclusive prefix of this thread's chunk
    for (int i = begin; i < end; ++i) { row_start[i] = run; run += deg[i]; }
}

__global__ void k_fill(const int* __restrict__ srcA, const int* __restrict__ dstA, int E,
                       const int* __restrict__ row_start, int* __restrict__ counts,
                       int* __restrict__ csr) {
    int e = blockIdx.x * blockDim.x + threadIdx.x;
    if (e < E) {
        int d = dstA[e];
        int slot = atomicAdd(&counts[d], 1);
        csr[row_start[d] + slot] = srcA[e];
    }
}

// ---------------------------------------------------------------------------
// Layer 1: h1 = x @ W1 ; alpha_src/dst per head.  One 64-lane wave per node,
// lane j computes h1[n, j]; per-8-lane shuffle reduce for the alphas.
// ---------------------------------------------------------------------------
__global__ void k_h1(const float* __restrict__ x, const float* __restrict__ W1,
                     const float* __restrict__ a_src, const float* __restrict__ a_dst,
                     int N, float* __restrict__ h1,
                     float* __restrict__ as1, float* __restrict__ ad1) {
    __shared__ float Ws[7 * 64];
    int tid = threadIdx.x;
    for (int i = tid; i < 7 * 64; i += blockDim.x) Ws[i] = W1[i];
    __syncthreads();
    int n = blockIdx.x * 4 + (tid >> 6);
    int lane = tid & 63;
    if (n >= N) return;
    float xv[7];
#pragma unroll
    for (int k = 0; k < 7; ++k) xv[k] = x[n * 7 + k];
    float hv = 0.f;
#pragma unroll
    for (int k = 0; k < 7; ++k) hv += xv[k] * Ws[k * 64 + lane];
    h1[n * 64 + lane] = hv;
    // alpha partials: lane = h*8 + c, a_src[h*8+c] = a_src[lane]
    float ps = hv * a_src[lane];
    float pd = hv * a_dst[lane];
#pragma unroll
    for (int off = 1; off < 8; off <<= 1) {
        ps += __shfl_xor(ps, off);
        pd += __shfl_xor(pd, off);
    }
    if ((lane & 7) == 0) {
        as1[n * 8 + (lane >> 3)] = ps;
        ad1[n * 8 + (lane >> 3)] = pd;
    }
}

// ---------------------------------------------------------------------------
// Layer 1 aggregation + bias + ELU.  One wave per dst node; lane = h*8+c.
// softmax without max-subtraction (values are O(1); mathematically identical).
// ---------------------------------------------------------------------------
__global__ void k_agg1(const float* __restrict__ h1, const float* __restrict__ as1,
                       const float* __restrict__ ad1, const int* __restrict__ deg,
                       const int* __restrict__ row_start, const int* __restrict__ csr,
                       const float* __restrict__ b1, int N, float* __restrict__ helu) {
    int n = blockIdx.x * 4 + (threadIdx.x >> 6);
    int lane = threadIdx.x & 63;
    if (n >= N) return;
    int h = lane >> 3;
    float adv = ad1[n * 8 + h];
    int d = deg[n];
    int start = row_start[n];
    float acc = 0.f, den = 0.f;
    for (int i = 0; i < d; ++i) {
        int src = csr[start + i];
        float ev = as1[src * 8 + h] + adv;
        ev = ev > 0.f ? ev : NEG_SLOPE * ev;
        float w = __expf(ev);
        den += w;
        acc += w * h1[src * 64 + lane];
    }
    // self loop
    {
        float ev = as1[n * 8 + h] + adv;
        ev = ev > 0.f ? ev : NEG_SLOPE * ev;
        float w = __expf(ev);
        den += w;
        acc += w * h1[n * 64 + lane];
    }
    float o = acc / den + b1[lane];
    helu[n * 64 + lane] = o > 0.f ? o : (__expf(o) - 1.f);  // ELU (alpha=1)
}

// ---------------------------------------------------------------------------
// Layer 2 projection: h2 = helu @ W2 (64 -> 2), plus alpha scalars.
// One wave per node; full-wave shuffle reduction of the 2 dot products.
// ---------------------------------------------------------------------------
__global__ void k_h2(const float* __restrict__ helu, const float* __restrict__ W2,
                     const float* __restrict__ as2w, const float* __restrict__ ad2w,
                     int N, float* __restrict__ h2,
                     float* __restrict__ as2, float* __restrict__ ad2) {
    int n = blockIdx.x * 4 + (threadIdx.x >> 6);
    int lane = threadIdx.x & 63;
    if (n >= N) return;
    float v = helu[n * 64 + lane];
    float p0 = v * W2[lane * 2 + 0];
    float p1 = v * W2[lane * 2 + 1];
#pragma unroll
    for (int off = 1; off < 64; off <<= 1) {
        p0 += __shfl_xor(p0, off);
        p1 += __shfl_xor(p1, off);
    }
    if (lane == 0) {
        h2[n * 2 + 0] = p0;
        h2[n * 2 + 1] = p1;
        as2[n] = p0 * as2w[0] + p1 * as2w[1];
        ad2[n] = p0 * ad2w[0] + p1 * ad2w[1];
    }
}

// ---------------------------------------------------------------------------
// Layer 2 aggregation + bias + log_softmax (2 classes), fused final output.
// One wave per dst; lanes stride over incoming edges (coalesced CSR reads).
// ---------------------------------------------------------------------------
__global__ void k_agg2(const float* __restrict__ h2, const float* __restrict__ as2,
                       const float* __restrict__ ad2, const int* __restrict__ deg,
                       const int* __restrict__ row_start, const int* __restrict__ csr,
                       const float* __restrict__ b2, int N, float* __restrict__ out) {
    int n = blockIdx.x * 4 + (threadIdx.x >> 6);
    int lane = threadIdx.x & 63;
    if (n >= N) return;
    float adv = ad2[n];
    int d = deg[n], start = row_start[n];
    float den = 0.f, a0 = 0.f, a1 = 0.f;
    for (int i = lane; i < d; i += 64) {
        int src = csr[start + i];
        float ev = as2[src] + adv;
        ev = ev > 0.f ? ev : NEG_SLOPE * ev;
        float w = __expf(ev);
        den += w;
        a0 += w * h2[src * 2 + 0];
        a1 += w * h2[src * 2 + 1];
    }
#pragma unroll
    for (int off = 1; off < 64; off <<= 1) {
        den += __shfl_xor(den, off);
        a0  += __shfl_xor(a0, off);
        a1  += __shfl_xor(a1, off);
    }
    if (lane == 0) {
        // self loop
        float ev = as2[n] + adv;
        ev = ev > 0.f ? ev : NEG_SLOPE * ev;
        float w = __expf(ev);
        den += w;
        a0 += w * h2[n * 2 + 0];
        a1 += w * h2[n * 2 + 1];
        float o0 = a0 / den + b2[0];
        float o1 = a1 / den + b2[1];
        float m = fmaxf(o0, o1);
        float lse = m + logf(__expf(o0 - m) + __expf(o1 - m));
        out[n * 2 + 0] = o0 - lse;
        out[n * 2 + 1] = o1 - lse;
    }
}

// ---------------------------------------------------------------------------
extern "C" void kernel_launch(void* const* d_in, const int* in_sizes, int n_in,
                              void* d_out, int out_size, void* d_ws, size_t ws_size,
                              hipStream_t stream) {
    const float* x     = (const float*)d_in[0];
    const int*   ei    = (const int*)d_in[1];   // [2, E] flattened: src then dst
    const float* W1    = (const float*)d_in[2];
    const float* as1w  = (const float*)d_in[3];
    const float* ad1w  = (const float*)d_in[4];
    const float* b1    = (const float*)d_in[5];
    const float* W2    = (const float*)d_in[6];
    const float* as2w  = (const float*)d_in[7];
    const float* ad2w  = (const float*)d_in[8];
    const float* b2    = (const float*)d_in[9];
    float* out = (float*)d_out;

    const int N = in_sizes[0] / 7;
    const int E = in_sizes[1] / 2;
    const int* srcA = ei;
    const int* dstA = ei + E;

    // workspace carve-up (256B aligned)
    size_t off = 0;
    auto alloc = [&](size_t bytes) -> void* {
        void* p = (char*)d_ws + off;
        off += (bytes + 255) & ~(size_t)255;
        return p;
    };
    float* h1   = (float*)alloc((size_t)N * 64 * 4);
    float* helu = (float*)alloc((size_t)N * 64 * 4);
    float* as1  = (float*)alloc((size_t)N * 8 * 4);
    float* ad1  = (float*)alloc((size_t)N * 8 * 4);
    float* h2   = (float*)alloc((size_t)N * 2 * 4);
    float* as2  = (float*)alloc((size_t)N * 4);
    float* ad2  = (float*)alloc((size_t)N * 4);
    int*   deg  = (int*)alloc((size_t)N * 4);
    int*   rows = (int*)alloc((size_t)N * 4);
    int*   cnts = (int*)alloc((size_t)N * 4);
    int*   csr  = (int*)alloc((size_t)E * 4);

    hipMemsetAsync(deg,  0, (size_t)N * 4, stream);
    hipMemsetAsync(cnts, 0, (size_t)N * 4, stream);

    const int eb = (E + 255) / 256;
    const int nb = (N + 3) / 4;   // 4 waves (nodes) per 256-thread block

    k_degree<<<eb, 256, 0, stream>>>(dstA, E, deg);
    k_scan<<<1, 1024, 0, stream>>>(deg, rows, N);
    k_fill<<<eb, 256, 0, stream>>>(srcA, dstA, E, rows, cnts, csr);

    k_h1<<<nb, 256, 0, stream>>>(x, W1, as1w, ad1w, N, h1, as1, ad1);
    k_agg1<<<nb, 256, 0, stream>>>(h1, as1, ad1, deg, rows, csr, b1, N, helu);
    k_h2<<<nb, 256, 0, stream>>>(helu, W2, as2w, ad2w, N, h2, as2, ad2);
    k_agg2<<<nb, 256, 0, stream>>>(h2, as2, ad2, deg, rows, csr, b2, N, out);
}

// Round 2
// 745.256 us; speedup vs baseline: 1.2505x; 1.2505x over previous
//
#include <hip/hip_runtime.h>
#include <math.h>

#define NEG_SLOPE 0.2f

__device__ __forceinline__ float bf2f(unsigned short u) {
    return __uint_as_float(((unsigned int)u) << 16);
}
__device__ __forceinline__ unsigned short f2bf(float f) {  // RNE
    unsigned int u = __float_as_uint(f);
    u += 0x7FFFu + ((u >> 16) & 1u);
    return (unsigned short)(u >> 16);
}
__device__ __forceinline__ float lrelu(float v) {
    return v > 0.f ? v : NEG_SLOPE * v;
}

// ---------------------------------------------------------------------------
// CSR build: degree count -> exclusive scan -> scatter
// ---------------------------------------------------------------------------
__global__ void k_degree(const int* __restrict__ dstA, int E, int* __restrict__ deg) {
    int e = blockIdx.x * blockDim.x + threadIdx.x;
    if (e < E) atomicAdd(&deg[dstA[e]], 1);
}

__global__ void k_scan(const int* __restrict__ deg, int* __restrict__ row_start, int N) {
    __shared__ int sums[1024];
    int tid = threadIdx.x;
    int chunk = (N + 1023) >> 10;
    int begin = tid * chunk;
    int end = begin + chunk; if (end > N) end = N; if (begin > N) begin = N;
    int s = 0;
    for (int i = begin; i < end; ++i) s += deg[i];
    sums[tid] = s;
    __syncthreads();
    for (int off = 1; off < 1024; off <<= 1) {
        int t = (tid >= off) ? sums[tid - off] : 0;
        __syncthreads();
        sums[tid] += t;
        __syncthreads();
    }
    int run = sums[tid] - s;
    for (int i = begin; i < end; ++i) { row_start[i] = run; run += deg[i]; }
}

__global__ void k_fill(const int* __restrict__ srcA, const int* __restrict__ dstA, int E,
                       const int* __restrict__ row_start, int* __restrict__ counts,
                       int* __restrict__ csr) {
    int e = blockIdx.x * blockDim.x + threadIdx.x;
    if (e < E) {
        int d = dstA[e];
        int slot = atomicAdd(&counts[d], 1);
        csr[row_start[d] + slot] = srcA[e];
    }
}

// ---------------------------------------------------------------------------
// Layer 1 projection: h1(bf16) = x @ W1, alpha scalars fp32.
// One wave per node, lane j = feature j (= h*8+c).
// ---------------------------------------------------------------------------
__global__ void k_h1(const float* __restrict__ x, const float* __restrict__ W1,
                     const float* __restrict__ a_src, const float* __restrict__ a_dst,
                     int N, unsigned short* __restrict__ h1b,
                     float* __restrict__ as1, float* __restrict__ ad1) {
    __shared__ float Ws[7 * 64];
    int tid = threadIdx.x;
    for (int i = tid; i < 7 * 64; i += blockDim.x) Ws[i] = W1[i];
    __syncthreads();
    int n = blockIdx.x * 4 + (tid >> 6);
    int lane = tid & 63;
    if (n >= N) return;
    float xv[7];
#pragma unroll
    for (int k = 0; k < 7; ++k) xv[k] = x[n * 7 + k];
    float hv = 0.f;
#pragma unroll
    for (int k = 0; k < 7; ++k) hv += xv[k] * Ws[k * 64 + lane];
    h1b[(size_t)n * 64 + lane] = f2bf(hv);
    float ps = hv * a_src[lane];
    float pd = hv * a_dst[lane];
#pragma unroll
    for (int off = 1; off < 8; off <<= 1) {
        ps += __shfl_xor(ps, off);
        pd += __shfl_xor(pd, off);
    }
    if ((lane & 7) == 0) {
        as1[n * 8 + (lane >> 3)] = ps;
        ad1[n * 8 + (lane >> 3)] = pd;
    }
}

// ---------------------------------------------------------------------------
// Layer 1 aggregation + bias + ELU, FUSED with layer-2 projection (64->2)
// and layer-2 alpha scalars.  One wave per dst node; lane = h*8+c.
// 4-edge unroll for memory-level parallelism.
// ---------------------------------------------------------------------------
__global__ void k_agg1(const unsigned short* __restrict__ h1b,
                       const float* __restrict__ as1, const float* __restrict__ ad1,
                       const int* __restrict__ deg, const int* __restrict__ rows,
                       const int* __restrict__ csr, const float* __restrict__ b1,
                       const float* __restrict__ W2, const float* __restrict__ as2w,
                       const float* __restrict__ ad2w, int N,
                       float* __restrict__ h2, float* __restrict__ as2,
                       float* __restrict__ ad2) {
    int n = blockIdx.x * 4 + (threadIdx.x >> 6);
    int lane = threadIdx.x & 63;
    if (n >= N) return;
    int h = lane >> 3;
    float adv = ad1[n * 8 + h];
    int d = deg[n];
    int start = rows[n];
    float acc = 0.f, den = 0.f;
    int i = 0;
    for (; i + 4 <= d; i += 4) {
        int s0 = csr[start + i + 0];
        int s1 = csr[start + i + 1];
        int s2 = csr[start + i + 2];
        int s3 = csr[start + i + 3];
        float e0 = as1[s0 * 8 + h];
        float e1 = as1[s1 * 8 + h];
        float e2 = as1[s2 * 8 + h];
        float e3 = as1[s3 * 8 + h];
        unsigned short u0 = h1b[(size_t)s0 * 64 + lane];
        unsigned short u1 = h1b[(size_t)s1 * 64 + lane];
        unsigned short u2 = h1b[(size_t)s2 * 64 + lane];
        unsigned short u3 = h1b[(size_t)s3 * 64 + lane];
        float w0 = __expf(lrelu(e0 + adv));
        float w1 = __expf(lrelu(e1 + adv));
        float w2 = __expf(lrelu(e2 + adv));
        float w3 = __expf(lrelu(e3 + adv));
        den += (w0 + w1) + (w2 + w3);
        acc += w0 * bf2f(u0) + w1 * bf2f(u1) + w2 * bf2f(u2) + w3 * bf2f(u3);
    }
    for (; i < d; ++i) {
        int s = csr[start + i];
        float w = __expf(lrelu(as1[s * 8 + h] + adv));
        den += w;
        acc += w * bf2f(h1b[(size_t)s * 64 + lane]);
    }
    {   // self loop
        float w = __expf(lrelu(as1[n * 8 + h] + adv));
        den += w;
        acc += w * bf2f(h1b[(size_t)n * 64 + lane]);
    }
    float o = acc / den + b1[lane];
    float v = o > 0.f ? o : (__expf(o) - 1.f);  // ELU
    // fused layer-2 projection: p = v . W2[:,0..1], wave-reduced
    float p0 = v * W2[lane * 2 + 0];
    float p1 = v * W2[lane * 2 + 1];
#pragma unroll
    for (int off = 1; off < 64; off <<= 1) {
        p0 += __shfl_xor(p0, off);
        p1 += __shfl_xor(p1, off);
    }
    if (lane == 0) {
        h2[n * 2 + 0] = p0;
        h2[n * 2 + 1] = p1;
        as2[n] = p0 * as2w[0] + p1 * as2w[1];
        ad2[n] = p0 * ad2w[0] + p1 * ad2w[1];
    }
}

// ---------------------------------------------------------------------------
// Layer 2 aggregation + bias + log_softmax (2 classes), fused final output.
// One wave per dst; lanes stride over incoming edges (coalesced CSR reads).
// ---------------------------------------------------------------------------
__global__ void k_agg2(const float* __restrict__ h2, const float* __restrict__ as2,
                       const float* __restrict__ ad2, const int* __restrict__ deg,
                       const int* __restrict__ rows, const int* __restrict__ csr,
                       const float* __restrict__ b2, int N, float* __restrict__ out) {
    int n = blockIdx.x * 4 + (threadIdx.x >> 6);
    int lane = threadIdx.x & 63;
    if (n >= N) return;
    const float2* __restrict__ h22 = (const float2*)h2;
    float adv = ad2[n];
    int d = deg[n], start = rows[n];
    float den = 0.f, a0 = 0.f, a1 = 0.f;
    for (int i = lane; i < d; i += 64) {
        int src = csr[start + i];
        float w = __expf(lrelu(as2[src] + adv));
        float2 hv = h22[src];
        den += w;
        a0 += w * hv.x;
        a1 += w * hv.y;
    }
#pragma unroll
    for (int off = 1; off < 64; off <<= 1) {
        den += __shfl_xor(den, off);
        a0  += __shfl_xor(a0, off);
        a1  += __shfl_xor(a1, off);
    }
    if (lane == 0) {
        float w = __expf(lrelu(as2[n] + adv));  // self loop
        float2 hv = h22[n];
        den += w;
        a0 += w * hv.x;
        a1 += w * hv.y;
        float o0 = a0 / den + b2[0];
        float o1 = a1 / den + b2[1];
        float m = fmaxf(o0, o1);
        float lse = m + logf(__expf(o0 - m) + __expf(o1 - m));
        out[n * 2 + 0] = o0 - lse;
        out[n * 2 + 1] = o1 - lse;
    }
}

// ---------------------------------------------------------------------------
extern "C" void kernel_launch(void* const* d_in, const int* in_sizes, int n_in,
                              void* d_out, int out_size, void* d_ws, size_t ws_size,
                              hipStream_t stream) {
    const float* x     = (const float*)d_in[0];
    const int*   ei    = (const int*)d_in[1];   // [2, E] flattened: src then dst
    const float* W1    = (const float*)d_in[2];
    const float* as1w  = (const float*)d_in[3];
    const float* ad1w  = (const float*)d_in[4];
    const float* b1    = (const float*)d_in[5];
    const float* W2    = (const float*)d_in[6];
    const float* as2w  = (const float*)d_in[7];
    const float* ad2w  = (const float*)d_in[8];
    const float* b2    = (const float*)d_in[9];
    float* out = (float*)d_out;

    const int N = in_sizes[0] / 7;
    const int E = in_sizes[1] / 2;
    const int* srcA = ei;
    const int* dstA = ei + E;

    size_t off = 0;
    auto alloc = [&](size_t bytes) -> void* {
        void* p = (char*)d_ws + off;
        off += (bytes + 255) & ~(size_t)255;
        return p;
    };
    unsigned short* h1b = (unsigned short*)alloc((size_t)N * 64 * 2);
    float* as1  = (float*)alloc((size_t)N * 8 * 4);
    float* ad1  = (float*)alloc((size_t)N * 8 * 4);
    float* h2   = (float*)alloc((size_t)N * 2 * 4);
    float* as2  = (float*)alloc((size_t)N * 4);
    float* ad2  = (float*)alloc((size_t)N * 4);
    int*   deg  = (int*)alloc((size_t)N * 4);
    int*   rows = (int*)alloc((size_t)N * 4);
    int*   cnts = (int*)alloc((size_t)N * 4);
    int*   csr  = (int*)alloc((size_t)E * 4);

    hipMemsetAsync(deg,  0, (size_t)N * 4, stream);
    hipMemsetAsync(cnts, 0, (size_t)N * 4, stream);

    const int eb = (E + 255) / 256;
    const int nb = (N + 3) / 4;

    k_degree<<<eb, 256, 0, stream>>>(dstA, E, deg);
    k_scan<<<1, 1024, 0, stream>>>(deg, rows, N);
    k_fill<<<eb, 256, 0, stream>>>(srcA, dstA, E, rows, cnts, csr);

    k_h1<<<nb, 256, 0, stream>>>(x, W1, as1w, ad1w, N, h1b, as1, ad1);
    k_agg1<<<nb, 256, 0, stream>>>(h1b, as1, ad1, deg, rows, csr, b1,
                                   W2, as2w, ad2w, N, h2, as2, ad2);
    k_agg2<<<nb, 256, 0, stream>>>(h2, as2, ad2, deg, rows, csr, b2, N, out);
}

// Round 3
// 363.150 us; speedup vs baseline: 2.5662x; 2.0522x over previous
//
#include <hip/hip_runtime.h>
#include <math.h>

#define NEG_SLOPE 0.2f
#define NPB_SHIFT 8              // nodes per bucket = 256
#define NBMAX 512                // supports N <= 131072
#define SC_EDGES 8192            // edges staged per scatter block (256 thr * 32)

__device__ __forceinline__ float bf2f(unsigned short u) {
    return __uint_as_float(((unsigned int)u) << 16);
}
__device__ __forceinline__ unsigned short f2bf(float f) {  // RNE
    unsigned int u = __float_as_uint(f);
    u += 0x7FFFu + ((u >> 16) & 1u);
    return (unsigned short)(u >> 16);
}
__device__ __forceinline__ float lrelu(float v) {
    return v > 0.f ? v : NEG_SLOPE * v;
}

// ---------------------------------------------------------------------------
// Pass 0: global coarse-bucket histogram (LDS-accumulated)
// ---------------------------------------------------------------------------
__global__ void k_hist(const int* __restrict__ dstA, int E, int NB,
                       int* __restrict__ gcount) {
    __shared__ int hist[NBMAX];
    for (int i = threadIdx.x; i < NBMAX; i += blockDim.x) hist[i] = 0;
    __syncthreads();
    int stride = gridDim.x * blockDim.x;
    for (int i = blockIdx.x * blockDim.x + threadIdx.x; i < E; i += stride)
        atomicAdd(&hist[dstA[i] >> NPB_SHIFT], 1);
    __syncthreads();
    for (int b = threadIdx.x; b < NB; b += blockDim.x) {
        int c = hist[b];
        if (c) atomicAdd(&gcount[b], c);
    }
}

// ---------------------------------------------------------------------------
// Pass 0b: scan bucket counts -> bucket_start[NB+1]; init global cursors
// ---------------------------------------------------------------------------
__global__ void k_bscan(const int* __restrict__ gcount, int NB,
                        int* __restrict__ bucket_start, int* __restrict__ cursor_g) {
    __shared__ int s[NBMAX];
    int t = threadIdx.x;
    int v = (t < NB) ? gcount[t] : 0;
    s[t] = v;
    __syncthreads();
    for (int off = 1; off < NBMAX; off <<= 1) {
        int u = (t >= off) ? s[t - off] : 0;
        __syncthreads();
        s[t] += u;
        __syncthreads();
    }
    int ex = s[t] - v;
    if (t < NB) { bucket_start[t] = ex; cursor_g[t] = ex; }
    if (t == NB - 1) bucket_start[NB] = ex + v;
}

// ---------------------------------------------------------------------------
// Pass 1: scatter edges into bucket regions, LDS-staged so global writes are
// contiguous per bucket segment (~1.4x write amplification vs 16x naive).
// payload = (dst<<32) | src
// ---------------------------------------------------------------------------
__global__ void k_scatter(const int* __restrict__ srcA, const int* __restrict__ dstA,
                          int E, int NB, int* __restrict__ cursor_g,
                          unsigned long long* __restrict__ payload) {
    __shared__ unsigned long long stage[SC_EDGES];
    __shared__ int hist[NBMAX], scanb[NBMAX], cur2[NBMAX], gbase[NBMAX];
    __shared__ int ssum[256];
    int t = threadIdx.x;
    int base = blockIdx.x * SC_EDGES;
    int cnt = E - base; if (cnt > SC_EDGES) cnt = SC_EDGES;

    for (int i = t; i < NBMAX; i += 256) hist[i] = 0;
    __syncthreads();
    // count
    for (int k = 0; k < 32; ++k) {
        int j = k * 256 + t;
        if (j < cnt) atomicAdd(&hist[dstA[base + j] >> NPB_SHIFT], 1);
    }
    __syncthreads();
    // exclusive scan over NBMAX=512 entries with 256 threads
    int a0 = hist[2 * t], a1 = hist[2 * t + 1];
    ssum[t] = a0 + a1;
    __syncthreads();
    for (int off = 1; off < 256; off <<= 1) {
        int u = (t >= off) ? ssum[t - off] : 0;
        __syncthreads();
        ssum[t] += u;
        __syncthreads();
    }
    int ex = ssum[t] - (a0 + a1);
    scanb[2 * t] = ex;
    scanb[2 * t + 1] = ex + a0;
    cur2[2 * t] = 0;
    cur2[2 * t + 1] = 0;
    __syncthreads();
    // reserve contiguous global ranges (one atomic per non-empty bucket)
    for (int b = t; b < NB; b += 256) {
        int c = hist[b];
        gbase[b] = c ? atomicAdd(&cursor_g[b], c) : 0;
    }
    __syncthreads();
    // stage ordered by bucket
    for (int k = 0; k < 32; ++k) {
        int j = k * 256 + t;
        if (j < cnt) {
            int s = srcA[base + j];
            int d = dstA[base + j];
            int b = d >> NPB_SHIFT;
            int pos = scanb[b] + atomicAdd(&cur2[b], 1);
            stage[pos] = ((unsigned long long)(unsigned int)d << 32) | (unsigned int)s;
        }
    }
    __syncthreads();
    // write out: consecutive staged slots within a bucket -> consecutive global
    for (int k = 0; k < 32; ++k) {
        int j = k * 256 + t;
        if (j < cnt) {
            unsigned long long p = stage[j];
            int b = (int)(p >> (32 + NPB_SHIFT));
            payload[gbase[b] + (j - scanb[b])] = p;
        }
    }
}

// ---------------------------------------------------------------------------
// Pass 2: one workgroup per bucket -> exact CSR (deg, rows, csr[src]).
// All scatter writes land in this bucket's ~32 KB region (single CU, L2-local).
// ---------------------------------------------------------------------------
__global__ void k_buildcsr(const unsigned long long* __restrict__ payload,
                           const int* __restrict__ bucket_start, int N,
                           int* __restrict__ deg, int* __restrict__ rows,
                           int* __restrict__ csr) {
    __shared__ int hist[256], scanb[256], cur[256];
    int b = blockIdx.x;
    int t = threadIdx.x;
    int bs = bucket_start[b], be = bucket_start[b + 1];
    int nodeBase = b << NPB_SHIFT;
    int nNodes = N - nodeBase; if (nNodes > 256) nNodes = 256;
    hist[t] = 0;
    __syncthreads();
    for (int i = bs + t; i < be; i += 256)
        atomicAdd(&hist[(int)(payload[i] >> 32) & 255], 1);
    __syncthreads();
    int own = hist[t];
    scanb[t] = own;
    __syncthreads();
    for (int off = 1; off < 256; off <<= 1) {
        int u = (t >= off) ? scanb[t - off] : 0;
        __syncthreads();
        scanb[t] += u;
        __syncthreads();
    }
    int ex = scanb[t] - own;
    if (t < nNodes) { deg[nodeBase + t] = own; rows[nodeBase + t] = bs + ex; }
    cur[t] = ex;
    __syncthreads();
    for (int i = bs + t; i < be; i += 256) {
        unsigned long long p = payload[i];
        int dl = (int)(p >> 32) & 255;
        int slot = atomicAdd(&cur[dl], 1);
        csr[bs + slot] = (int)(unsigned int)p;
    }
}

// ---------------------------------------------------------------------------
// Layer 1 projection: h1(bf16) = x @ W1, alpha scalars fp32.
// ---------------------------------------------------------------------------
__global__ void k_h1(const float* __restrict__ x, const float* __restrict__ W1,
                     const float* __restrict__ a_src, const float* __restrict__ a_dst,
                     int N, unsigned short* __restrict__ h1b,
                     float* __restrict__ as1, float* __restrict__ ad1) {
    __shared__ float Ws[7 * 64];
    int tid = threadIdx.x;
    for (int i = tid; i < 7 * 64; i += blockDim.x) Ws[i] = W1[i];
    __syncthreads();
    int n = blockIdx.x * 4 + (tid >> 6);
    int lane = tid & 63;
    if (n >= N) return;
    float xv[7];
#pragma unroll
    for (int k = 0; k < 7; ++k) xv[k] = x[n * 7 + k];
    float hv = 0.f;
#pragma unroll
    for (int k = 0; k < 7; ++k) hv += xv[k] * Ws[k * 64 + lane];
    h1b[(size_t)n * 64 + lane] = f2bf(hv);
    float ps = hv * a_src[lane];
    float pd = hv * a_dst[lane];
#pragma unroll
    for (int off = 1; off < 8; off <<= 1) {
        ps += __shfl_xor(ps, off);
        pd += __shfl_xor(pd, off);
    }
    if ((lane & 7) == 0) {
        as1[n * 8 + (lane >> 3)] = ps;
        ad1[n * 8 + (lane >> 3)] = pd;
    }
}

// ---------------------------------------------------------------------------
// Layer 1 aggregation + bias + ELU, fused with layer-2 projection (64->2).
// ---------------------------------------------------------------------------
__global__ void k_agg1(const unsigned short* __restrict__ h1b,
                       const float* __restrict__ as1, const float* __restrict__ ad1,
                       const int* __restrict__ deg, const int* __restrict__ rows,
                       const int* __restrict__ csr, const float* __restrict__ b1,
                       const float* __restrict__ W2, const float* __restrict__ as2w,
                       const float* __restrict__ ad2w, int N,
                       float* __restrict__ h2, float* __restrict__ as2,
                       float* __restrict__ ad2) {
    int n = blockIdx.x * 4 + (threadIdx.x >> 6);
    int lane = threadIdx.x & 63;
    if (n >= N) return;
    int h = lane >> 3;
    float adv = ad1[n * 8 + h];
    int d = deg[n];
    int start = rows[n];
    float acc = 0.f, den = 0.f;
    int i = 0;
    for (; i + 4 <= d; i += 4) {
        int s0 = csr[start + i + 0];
        int s1 = csr[start + i + 1];
        int s2 = csr[start + i + 2];
        int s3 = csr[start + i + 3];
        float e0 = as1[s0 * 8 + h];
        float e1 = as1[s1 * 8 + h];
        float e2 = as1[s2 * 8 + h];
        float e3 = as1[s3 * 8 + h];
        unsigned short u0 = h1b[(size_t)s0 * 64 + lane];
        unsigned short u1 = h1b[(size_t)s1 * 64 + lane];
        unsigned short u2 = h1b[(size_t)s2 * 64 + lane];
        unsigned short u3 = h1b[(size_t)s3 * 64 + lane];
        float w0 = __expf(lrelu(e0 + adv));
        float w1 = __expf(lrelu(e1 + adv));
        float w2 = __expf(lrelu(e2 + adv));
        float w3 = __expf(lrelu(e3 + adv));
        den += (w0 + w1) + (w2 + w3);
        acc += w0 * bf2f(u0) + w1 * bf2f(u1) + w2 * bf2f(u2) + w3 * bf2f(u3);
    }
    for (; i < d; ++i) {
        int s = csr[start + i];
        float w = __expf(lrelu(as1[s * 8 + h] + adv));
        den += w;
        acc += w * bf2f(h1b[(size_t)s * 64 + lane]);
    }
    {   // self loop
        float w = __expf(lrelu(as1[n * 8 + h] + adv));
        den += w;
        acc += w * bf2f(h1b[(size_t)n * 64 + lane]);
    }
    float o = acc / den + b1[lane];
    float v = o > 0.f ? o : (__expf(o) - 1.f);  // ELU
    float p0 = v * W2[lane * 2 + 0];
    float p1 = v * W2[lane * 2 + 1];
#pragma unroll
    for (int off = 1; off < 64; off <<= 1) {
        p0 += __shfl_xor(p0, off);
        p1 += __shfl_xor(p1, off);
    }
    if (lane == 0) {
        h2[n * 2 + 0] = p0;
        h2[n * 2 + 1] = p1;
        as2[n] = p0 * as2w[0] + p1 * as2w[1];
        ad2[n] = p0 * ad2w[0] + p1 * ad2w[1];
    }
}

// ---------------------------------------------------------------------------
// Layer 2 aggregation + bias + log_softmax, fused final output.
// ---------------------------------------------------------------------------
__global__ void k_agg2(const float* __restrict__ h2, const float* __restrict__ as2,
                       const float* __restrict__ ad2, const int* __restrict__ deg,
                       const int* __restrict__ rows, const int* __restrict__ csr,
                       const float* __restrict__ b2, int N, float* __restrict__ out) {
    int n = blockIdx.x * 4 + (threadIdx.x >> 6);
    int lane = threadIdx.x & 63;
    if (n >= N) return;
    const float2* __restrict__ h22 = (const float2*)h2;
    float adv = ad2[n];
    int d = deg[n], start = rows[n];
    float den = 0.f, a0 = 0.f, a1 = 0.f;
    for (int i = lane; i < d; i += 64) {
        int src = csr[start + i];
        float w = __expf(lrelu(as2[src] + adv));
        float2 hv = h22[src];
        den += w;
        a0 += w * hv.x;
        a1 += w * hv.y;
    }
#pragma unroll
    for (int off = 1; off < 64; off <<= 1) {
        den += __shfl_xor(den, off);
        a0  += __shfl_xor(a0, off);
        a1  += __shfl_xor(a1, off);
    }
    if (lane == 0) {
        float w = __expf(lrelu(as2[n] + adv));  // self loop
        float2 hv = h22[n];
        den += w;
        a0 += w * hv.x;
        a1 += w * hv.y;
        float o0 = a0 / den + b2[0];
        float o1 = a1 / den + b2[1];
        float m = fmaxf(o0, o1);
        float lse = m + logf(__expf(o0 - m) + __expf(o1 - m));
        out[n * 2 + 0] = o0 - lse;
        out[n * 2 + 1] = o1 - lse;
    }
}

// ---------------------------------------------------------------------------
extern "C" void kernel_launch(void* const* d_in, const int* in_sizes, int n_in,
                              void* d_out, int out_size, void* d_ws, size_t ws_size,
                              hipStream_t stream) {
    const float* x     = (const float*)d_in[0];
    const int*   ei    = (const int*)d_in[1];
    const float* W1    = (const float*)d_in[2];
    const float* as1w  = (const float*)d_in[3];
    const float* ad1w  = (const float*)d_in[4];
    const float* b1    = (const float*)d_in[5];
    const float* W2    = (const float*)d_in[6];
    const float* as2w  = (const float*)d_in[7];
    const float* ad2w  = (const float*)d_in[8];
    const float* b2    = (const float*)d_in[9];
    float* out = (float*)d_out;

    const int N = in_sizes[0] / 7;
    const int E = in_sizes[1] / 2;
    const int* srcA = ei;
    const int* dstA = ei + E;
    const int NB = (N + ((1 << NPB_SHIFT) - 1)) >> NPB_SHIFT;

    size_t off = 0;
    auto alloc = [&](size_t bytes) -> void* {
        void* p = (char*)d_ws + off;
        off += (bytes + 255) & ~(size_t)255;
        return p;
    };
    // payload (8B/edge) is dead after k_buildcsr; h1b aliases its front.
    unsigned long long* payload = (unsigned long long*)alloc((size_t)E * 8);
    unsigned short* h1b = (unsigned short*)payload;   // N*64*2 <= E*8
    float* as1  = (float*)alloc((size_t)N * 8 * 4);
    float* ad1  = (float*)alloc((size_t)N * 8 * 4);
    float* h2   = (float*)alloc((size_t)N * 2 * 4);
    float* as2  = (float*)alloc((size_t)N * 4);
    float* ad2  = (float*)alloc((size_t)N * 4);
    int*   deg  = (int*)alloc((size_t)N * 4);
    int*   rows = (int*)alloc((size_t)N * 4);
    int*   csr  = (int*)alloc((size_t)E * 4);
    int*   gcount       = (int*)alloc(NBMAX * 4);
    int*   bucket_start = (int*)alloc((NBMAX + 1) * 4);
    int*   cursor_g     = (int*)alloc(NBMAX * 4);

    hipMemsetAsync(gcount, 0, NBMAX * 4, stream);

    const int nb = (N + 3) / 4;
    const int sb = (E + SC_EDGES - 1) / SC_EDGES;

    k_hist<<<1024, 256, 0, stream>>>(dstA, E, NB, gcount);
    k_bscan<<<1, NBMAX, 0, stream>>>(gcount, NB, bucket_start, cursor_g);
    k_scatter<<<sb, 256, 0, stream>>>(srcA, dstA, E, NB, cursor_g, payload);
    k_buildcsr<<<NB, 256, 0, stream>>>(payload, bucket_start, N, deg, rows, csr);

    k_h1<<<nb, 256, 0, stream>>>(x, W1, as1w, ad1w, N, h1b, as1, ad1);
    k_agg1<<<nb, 256, 0, stream>>>(h1b, as1, ad1, deg, rows, csr, b1,
                                   W2, as2w, ad2w, N, h2, as2, ad2);
    k_agg2<<<nb, 256, 0, stream>>>(h2, as2, ad2, deg, rows, csr, b2, N, out);
}

// Round 4
// 333.723 us; speedup vs baseline: 2.7925x; 1.0882x over previous
//
#include <hip/hip_runtime.h>
#include <math.h>

#define NEG_SLOPE 0.2f
#define L2E 1.4426950408889634f
#define NPB_SHIFT 8              // nodes per bucket = 256
#define NBMAX 512                // supports N <= 131072
#define SC_EDGES 8192            // edges staged per scatter block

__device__ __forceinline__ float bf2f(unsigned short u) {
    return __uint_as_float(((unsigned int)u) << 16);
}
__device__ __forceinline__ unsigned short f2bf(float f) {  // RNE
    unsigned int u = __float_as_uint(f);
    u += 0x7FFFu + ((u >> 16) & 1u);
    return (unsigned short)(u >> 16);
}
__device__ __forceinline__ float lrelu(float v) {
    return v > 0.f ? v : NEG_SLOPE * v;
}

// ---------------------------------------------------------------------------
// Pass 0: global coarse-bucket histogram (LDS-accumulated)
// ---------------------------------------------------------------------------
__global__ void k_hist(const int* __restrict__ dstA, int E, int NB,
                       int* __restrict__ gcount) {
    __shared__ int hist[NBMAX];
    for (int i = threadIdx.x; i < NBMAX; i += blockDim.x) hist[i] = 0;
    __syncthreads();
    int stride = gridDim.x * blockDim.x;
    for (int i = blockIdx.x * blockDim.x + threadIdx.x; i < E; i += stride)
        atomicAdd(&hist[dstA[i] >> NPB_SHIFT], 1);
    __syncthreads();
    for (int b = threadIdx.x; b < NB; b += blockDim.x) {
        int c = hist[b];
        if (c) atomicAdd(&gcount[b], c);
    }
}

// ---------------------------------------------------------------------------
// Pass 0b: scan bucket counts -> bucket_start[NB+1]; init global cursors
// ---------------------------------------------------------------------------
__global__ void k_bscan(const int* __restrict__ gcount, int NB,
                        int* __restrict__ bucket_start, int* __restrict__ cursor_g) {
    __shared__ int s[NBMAX];
    int t = threadIdx.x;
    int v = (t < NB) ? gcount[t] : 0;
    s[t] = v;
    __syncthreads();
    for (int off = 1; off < NBMAX; off <<= 1) {
        int u = (t >= off) ? s[t - off] : 0;
        __syncthreads();
        s[t] += u;
        __syncthreads();
    }
    int ex = s[t] - v;
    if (t < NB) { bucket_start[t] = ex; cursor_g[t] = ex; }
    if (t == NB - 1) bucket_start[NB] = ex + v;
}

// ---------------------------------------------------------------------------
// Pass 1: scatter edges into bucket regions, LDS-staged so global writes are
// contiguous per bucket segment.  payload = (dst<<32) | src
// ---------------------------------------------------------------------------
__global__ void k_scatter(const int* __restrict__ srcA, const int* __restrict__ dstA,
                          int E, int NB, int* __restrict__ cursor_g,
                          unsigned long long* __restrict__ payload) {
    __shared__ unsigned long long stage[SC_EDGES];
    __shared__ int hist[NBMAX], scanb[NBMAX], cur2[NBMAX], gbase[NBMAX];
    __shared__ int ssum[256];
    int t = threadIdx.x;
    int base = blockIdx.x * SC_EDGES;
    int cnt = E - base; if (cnt > SC_EDGES) cnt = SC_EDGES;

    for (int i = t; i < NBMAX; i += 256) hist[i] = 0;
    __syncthreads();
    for (int k = 0; k < 32; ++k) {
        int j = k * 256 + t;
        if (j < cnt) atomicAdd(&hist[dstA[base + j] >> NPB_SHIFT], 1);
    }
    __syncthreads();
    int a0 = hist[2 * t], a1 = hist[2 * t + 1];
    ssum[t] = a0 + a1;
    __syncthreads();
    for (int off = 1; off < 256; off <<= 1) {
        int u = (t >= off) ? ssum[t - off] : 0;
        __syncthreads();
        ssum[t] += u;
        __syncthreads();
    }
    int ex = ssum[t] - (a0 + a1);
    scanb[2 * t] = ex;
    scanb[2 * t + 1] = ex + a0;
    cur2[2 * t] = 0;
    cur2[2 * t + 1] = 0;
    __syncthreads();
    for (int b = t; b < NB; b += 256) {
        int c = hist[b];
        gbase[b] = c ? atomicAdd(&cursor_g[b], c) : 0;
    }
    __syncthreads();
    for (int k = 0; k < 32; ++k) {
        int j = k * 256 + t;
        if (j < cnt) {
            int s = srcA[base + j];
            int d = dstA[base + j];
            int b = d >> NPB_SHIFT;
            int pos = scanb[b] + atomicAdd(&cur2[b], 1);
            stage[pos] = ((unsigned long long)(unsigned int)d << 32) | (unsigned int)s;
        }
    }
    __syncthreads();
    for (int k = 0; k < 32; ++k) {
        int j = k * 256 + t;
        if (j < cnt) {
            unsigned long long p = stage[j];
            int b = (int)(p >> (32 + NPB_SHIFT));
            payload[gbase[b] + (j - scanb[b])] = p;
        }
    }
}

// ---------------------------------------------------------------------------
// Pass 2: one workgroup per bucket -> exact CSR (deg, rows, csr[src]).
// ---------------------------------------------------------------------------
__global__ void k_buildcsr(const unsigned long long* __restrict__ payload,
                           const int* __restrict__ bucket_start, int N,
                           int* __restrict__ deg, int* __restrict__ rows,
                           int* __restrict__ csr) {
    __shared__ int hist[256], scanb[256], cur[256];
    int b = blockIdx.x;
    int t = threadIdx.x;
    int bs = bucket_start[b], be = bucket_start[b + 1];
    int nodeBase = b << NPB_SHIFT;
    int nNodes = N - nodeBase; if (nNodes > 256) nNodes = 256;
    hist[t] = 0;
    __syncthreads();
    for (int i = bs + t; i < be; i += 256)
        atomicAdd(&hist[(int)(payload[i] >> 32) & 255], 1);
    __syncthreads();
    int own = hist[t];
    scanb[t] = own;
    __syncthreads();
    for (int off = 1; off < 256; off <<= 1) {
        int u = (t >= off) ? scanb[t - off] : 0;
        __syncthreads();
        scanb[t] += u;
        __syncthreads();
    }
    int ex = scanb[t] - own;
    if (t < nNodes) { deg[nodeBase + t] = own; rows[nodeBase + t] = bs + ex; }
    cur[t] = ex;
    __syncthreads();
    for (int i = bs + t; i < be; i += 256) {
        unsigned long long p = payload[i];
        int dl = (int)(p >> 32) & 255;
        int slot = atomicAdd(&cur[dl], 1);
        csr[bs + slot] = (int)(unsigned int)p;
    }
}

// ---------------------------------------------------------------------------
// Layer 1 projection: h1(bf16) = x @ W1; alpha scalars pre-scaled by log2(e).
// ---------------------------------------------------------------------------
__global__ void k_h1(const float* __restrict__ x, const float* __restrict__ W1,
                     const float* __restrict__ a_src, const float* __restrict__ a_dst,
                     int N, unsigned short* __restrict__ h1b,
                     float* __restrict__ as1, float* __restrict__ ad1) {
    __shared__ float Ws[7 * 64];
    int tid = threadIdx.x;
    for (int i = tid; i < 7 * 64; i += blockDim.x) Ws[i] = W1[i];
    __syncthreads();
    int n = blockIdx.x * 4 + (tid >> 6);
    int lane = tid & 63;
    if (n >= N) return;
    float xv[7];
#pragma unroll
    for (int k = 0; k < 7; ++k) xv[k] = x[n * 7 + k];
    float hv = 0.f;
#pragma unroll
    for (int k = 0; k < 7; ++k) hv += xv[k] * Ws[k * 64 + lane];
    h1b[(size_t)n * 64 + lane] = f2bf(hv);
    float ps = hv * a_src[lane];
    float pd = hv * a_dst[lane];
#pragma unroll
    for (int off = 1; off < 8; off <<= 1) {
        ps += __shfl_xor(ps, off);
        pd += __shfl_xor(pd, off);
    }
    if ((lane & 7) == 0) {
        as1[n * 8 + (lane >> 3)] = ps * L2E;   // pre-scaled: exp(x) == exp2(x*L2E)
        ad1[n * 8 + (lane >> 3)] = pd * L2E;
    }
}

// ---------------------------------------------------------------------------
// Layer 1 aggregation + bias + ELU, fused with layer-2 projection (64->2).
// Scalarized row pointers & csr indices (SALU/SMEM); exp2-form softmax.
// Epilogue packs {p0, p1, as2*L2E, ad2*L2E} for layer-2.
// ---------------------------------------------------------------------------
__global__ void k_agg1(const unsigned short* __restrict__ h1b,
                       const float* __restrict__ as1, const float* __restrict__ ad1,
                       const int* __restrict__ deg, const int* __restrict__ rows,
                       const int* __restrict__ csr, const float* __restrict__ b1,
                       const float* __restrict__ W2, const float* __restrict__ as2w,
                       const float* __restrict__ ad2w, int N,
                       float4* __restrict__ pack) {
    int n = blockIdx.x * 4 + (threadIdx.x >> 6);
    int lane = threadIdx.x & 63;
    if (n >= N) return;
    n = __builtin_amdgcn_readfirstlane(n);   // wave-uniform by construction
    int h = lane >> 3;
    float adv = ad1[n * 8 + h];
    int d = deg[n];
    int start = rows[n];
    float acc = 0.f, den = 0.f;
    int i = 0;
    for (; i + 8 <= d; i += 8) {
        int s[8];
#pragma unroll
        for (int k = 0; k < 8; ++k)
            s[k] = __builtin_amdgcn_readfirstlane(csr[start + i + k]);
        float e[8];
#pragma unroll
        for (int k = 0; k < 8; ++k) e[k] = as1[s[k] * 8 + h];
        unsigned short u16[8];
#pragma unroll
        for (int k = 0; k < 8; ++k) u16[k] = h1b[(size_t)s[k] * 64 + lane];
#pragma unroll
        for (int k = 0; k < 8; ++k) {
            float w = exp2f(lrelu(e[k] + adv));
            den += w;
            acc += w * bf2f(u16[k]);
        }
    }
    for (; i < d; ++i) {
        int s = __builtin_amdgcn_readfirstlane(csr[start + i]);
        float w = exp2f(lrelu(as1[s * 8 + h] + adv));
        den += w;
        acc += w * bf2f(h1b[(size_t)s * 64 + lane]);
    }
    {   // self loop
        float w = exp2f(lrelu(as1[n * 8 + h] + adv));
        den += w;
        acc += w * bf2f(h1b[(size_t)n * 64 + lane]);
    }
    float o = acc / den + b1[lane];
    float v = o > 0.f ? o : (__expf(o) - 1.f);  // ELU
    float p0 = v * W2[lane * 2 + 0];
    float p1 = v * W2[lane * 2 + 1];
#pragma unroll
    for (int off = 1; off < 64; off <<= 1) {
        p0 += __shfl_xor(p0, off);
        p1 += __shfl_xor(p1, off);
    }
    if (lane == 0) {
        float4 pk;
        pk.x = p0;
        pk.y = p1;
        pk.z = (p0 * as2w[0] + p1 * as2w[1]) * L2E;
        pk.w = (p0 * ad2w[0] + p1 * ad2w[1]) * L2E;
        pack[n] = pk;
    }
}

// ---------------------------------------------------------------------------
// Layer 2 aggregation + bias + log_softmax: single float4 gather per edge.
// ---------------------------------------------------------------------------
__global__ void k_agg2(const float4* __restrict__ pack, const int* __restrict__ deg,
                       const int* __restrict__ rows, const int* __restrict__ csr,
                       const float* __restrict__ b2, int N, float* __restrict__ out) {
    int n = blockIdx.x * 4 + (threadIdx.x >> 6);
    int lane = threadIdx.x & 63;
    if (n >= N) return;
    n = __builtin_amdgcn_readfirstlane(n);
    float4 self = pack[n];
    float adv = self.w;
    int d = deg[n], start = rows[n];
    float den = 0.f, a0 = 0.f, a1 = 0.f;
    for (int i = lane; i < d; i += 64) {
        int src = csr[start + i];
        float4 q = pack[src];
        float w = exp2f(lrelu(q.z + adv));
        den += w;
        a0 += w * q.x;
        a1 += w * q.y;
    }
#pragma unroll
    for (int off = 1; off < 64; off <<= 1) {
        den += __shfl_xor(den, off);
        a0  += __shfl_xor(a0, off);
        a1  += __shfl_xor(a1, off);
    }
    if (lane == 0) {
        float w = exp2f(lrelu(self.z + adv));  // self loop
        den += w;
        a0 += w * self.x;
        a1 += w * self.y;
        float o0 = a0 / den + b2[0];
        float o1 = a1 / den + b2[1];
        float m = fmaxf(o0, o1);
        float lse = m + logf(__expf(o0 - m) + __expf(o1 - m));
        out[n * 2 + 0] = o0 - lse;
        out[n * 2 + 1] = o1 - lse;
    }
}

// ---------------------------------------------------------------------------
extern "C" void kernel_launch(void* const* d_in, const int* in_sizes, int n_in,
                              void* d_out, int out_size, void* d_ws, size_t ws_size,
                              hipStream_t stream) {
    const float* x     = (const float*)d_in[0];
    const int*   ei    = (const int*)d_in[1];
    const float* W1    = (const float*)d_in[2];
    const float* as1w  = (const float*)d_in[3];
    const float* ad1w  = (const float*)d_in[4];
    const float* b1    = (const float*)d_in[5];
    const float* W2    = (const float*)d_in[6];
    const float* as2w  = (const float*)d_in[7];
    const float* ad2w  = (const float*)d_in[8];
    const float* b2    = (const float*)d_in[9];
    float* out = (float*)d_out;

    const int N = in_sizes[0] / 7;
    const int E = in_sizes[1] / 2;
    const int* srcA = ei;
    const int* dstA = ei + E;
    const int NB = (N + ((1 << NPB_SHIFT) - 1)) >> NPB_SHIFT;

    size_t off = 0;
    auto alloc = [&](size_t bytes) -> void* {
        void* p = (char*)d_ws + off;
        off += (bytes + 255) & ~(size_t)255;
        return p;
    };
    // payload (8B/edge) is dead after k_buildcsr; h1b aliases its front.
    unsigned long long* payload = (unsigned long long*)alloc((size_t)E * 8);
    unsigned short* h1b = (unsigned short*)payload;   // N*64*2 <= E*8
    float* as1  = (float*)alloc((size_t)N * 8 * 4);
    float* ad1  = (float*)alloc((size_t)N * 8 * 4);
    float4* pack = (float4*)alloc((size_t)N * 16);
    int*   deg  = (int*)alloc((size_t)N * 4);
    int*   rows = (int*)alloc((size_t)N * 4);
    int*   csr  = (int*)alloc((size_t)E * 4);
    int*   gcount       = (int*)alloc(NBMAX * 4);
    int*   bucket_start = (int*)alloc((NBMAX + 1) * 4);
    int*   cursor_g     = (int*)alloc(NBMAX * 4);

    hipMemsetAsync(gcount, 0, NBMAX * 4, stream);

    const int nb = (N + 3) / 4;
    const int sb = (E + SC_EDGES - 1) / SC_EDGES;

    k_hist<<<1024, 256, 0, stream>>>(dstA, E, NB, gcount);
    k_bscan<<<1, NBMAX, 0, stream>>>(gcount, NB, bucket_start, cursor_g);
    k_scatter<<<sb, 256, 0, stream>>>(srcA, dstA, E, NB, cursor_g, payload);
    k_buildcsr<<<NB, 256, 0, stream>>>(payload, bucket_start, N, deg, rows, csr);

    k_h1<<<nb, 256, 0, stream>>>(x, W1, as1w, ad1w, N, h1b, as1, ad1);
    k_agg1<<<nb, 256, 0, stream>>>(h1b, as1, ad1, deg, rows, csr, b1,
                                   W2, as2w, ad2w, N, pack);
    k_agg2<<<nb, 256, 0, stream>>>(pack, deg, rows, csr, b2, N, out);
}

// Round 5
// 332.937 us; speedup vs baseline: 2.7991x; 1.0024x over previous
//
#include <hip/hip_runtime.h>
#include <math.h>

#define NEG_SLOPE 0.2f
#define L2E 1.4426950408889634f
#define NPB_SHIFT 8              // nodes per bucket = 256
#define NBMAX 512                // supports N <= 131072
#define SC_EDGES 8192            // edges staged per scatter block

__device__ __forceinline__ float bf2f(unsigned short u) {
    return __uint_as_float(((unsigned int)u) << 16);
}
__device__ __forceinline__ unsigned short f2bf(float f) {  // RNE
    unsigned int u = __float_as_uint(f);
    u += 0x7FFFu + ((u >> 16) & 1u);
    return (unsigned short)(u >> 16);
}
__device__ __forceinline__ float lrelu(float v) {
    return fmaxf(v, NEG_SLOPE * v);
}

// ---------------------------------------------------------------------------
// Pass 0: global coarse-bucket histogram (LDS-accumulated)
// ---------------------------------------------------------------------------
__global__ void k_hist(const int* __restrict__ dstA, int E, int NB,
                       int* __restrict__ gcount) {
    __shared__ int hist[NBMAX];
    for (int i = threadIdx.x; i < NBMAX; i += blockDim.x) hist[i] = 0;
    __syncthreads();
    int stride = gridDim.x * blockDim.x;
    for (int i = blockIdx.x * blockDim.x + threadIdx.x; i < E; i += stride)
        atomicAdd(&hist[dstA[i] >> NPB_SHIFT], 1);
    __syncthreads();
    for (int b = threadIdx.x; b < NB; b += blockDim.x) {
        int c = hist[b];
        if (c) atomicAdd(&gcount[b], c);
    }
}

// ---------------------------------------------------------------------------
// Pass 0b: scan bucket counts -> bucket_start[NB+1]; init global cursors
// ---------------------------------------------------------------------------
__global__ void k_bscan(const int* __restrict__ gcount, int NB,
                        int* __restrict__ bucket_start, int* __restrict__ cursor_g) {
    __shared__ int s[NBMAX];
    int t = threadIdx.x;
    int v = (t < NB) ? gcount[t] : 0;
    s[t] = v;
    __syncthreads();
    for (int off = 1; off < NBMAX; off <<= 1) {
        int u = (t >= off) ? s[t - off] : 0;
        __syncthreads();
        s[t] += u;
        __syncthreads();
    }
    int ex = s[t] - v;
    if (t < NB) { bucket_start[t] = ex; cursor_g[t] = ex; }
    if (t == NB - 1) bucket_start[NB] = ex + v;
}

// ---------------------------------------------------------------------------
// Pass 1: scatter edges into bucket regions, LDS-staged so global writes are
// contiguous per bucket segment.  payload = (dst<<32) | src
// ---------------------------------------------------------------------------
__global__ void k_scatter(const int* __restrict__ srcA, const int* __restrict__ dstA,
                          int E, int NB, int* __restrict__ cursor_g,
                          unsigned long long* __restrict__ payload) {
    __shared__ unsigned long long stage[SC_EDGES];
    __shared__ int hist[NBMAX], scanb[NBMAX], cur2[NBMAX], gbase[NBMAX];
    __shared__ int ssum[256];
    int t = threadIdx.x;
    int base = blockIdx.x * SC_EDGES;
    int cnt = E - base; if (cnt > SC_EDGES) cnt = SC_EDGES;

    for (int i = t; i < NBMAX; i += 256) hist[i] = 0;
    __syncthreads();
    for (int k = 0; k < 32; ++k) {
        int j = k * 256 + t;
        if (j < cnt) atomicAdd(&hist[dstA[base + j] >> NPB_SHIFT], 1);
    }
    __syncthreads();
    int a0 = hist[2 * t], a1 = hist[2 * t + 1];
    ssum[t] = a0 + a1;
    __syncthreads();
    for (int off = 1; off < 256; off <<= 1) {
        int u = (t >= off) ? ssum[t - off] : 0;
        __syncthreads();
        ssum[t] += u;
        __syncthreads();
    }
    int ex = ssum[t] - (a0 + a1);
    scanb[2 * t] = ex;
    scanb[2 * t + 1] = ex + a0;
    cur2[2 * t] = 0;
    cur2[2 * t + 1] = 0;
    __syncthreads();
    for (int b = t; b < NB; b += 256) {
        int c = hist[b];
        gbase[b] = c ? atomicAdd(&cursor_g[b], c) : 0;
    }
    __syncthreads();
    for (int k = 0; k < 32; ++k) {
        int j = k * 256 + t;
        if (j < cnt) {
            int s = srcA[base + j];
            int d = dstA[base + j];
            int b = d >> NPB_SHIFT;
            int pos = scanb[b] + atomicAdd(&cur2[b], 1);
            stage[pos] = ((unsigned long long)(unsigned int)d << 32) | (unsigned int)s;
        }
    }
    __syncthreads();
    for (int k = 0; k < 32; ++k) {
        int j = k * 256 + t;
        if (j < cnt) {
            unsigned long long p = stage[j];
            int b = (int)(p >> (32 + NPB_SHIFT));
            payload[gbase[b] + (j - scanb[b])] = p;
        }
    }
}

// ---------------------------------------------------------------------------
// Pass 2: one workgroup per bucket -> exact CSR (deg, rows, csr[src]).
// ---------------------------------------------------------------------------
__global__ void k_buildcsr(const unsigned long long* __restrict__ payload,
                           const int* __restrict__ bucket_start, int N,
                           int* __restrict__ deg, int* __restrict__ rows,
                           int* __restrict__ csr) {
    __shared__ int hist[256], scanb[256], cur[256];
    int b = blockIdx.x;
    int t = threadIdx.x;
    int bs = bucket_start[b], be = bucket_start[b + 1];
    int nodeBase = b << NPB_SHIFT;
    int nNodes = N - nodeBase; if (nNodes > 256) nNodes = 256;
    hist[t] = 0;
    __syncthreads();
    for (int i = bs + t; i < be; i += 256)
        atomicAdd(&hist[(int)(payload[i] >> 32) & 255], 1);
    __syncthreads();
    int own = hist[t];
    scanb[t] = own;
    __syncthreads();
    for (int off = 1; off < 256; off <<= 1) {
        int u = (t >= off) ? scanb[t - off] : 0;
        __syncthreads();
        scanb[t] += u;
        __syncthreads();
    }
    int ex = scanb[t] - own;
    if (t < nNodes) { deg[nodeBase + t] = own; rows[nodeBase + t] = bs + ex; }
    cur[t] = ex;
    __syncthreads();
    for (int i = bs + t; i < be; i += 256) {
        unsigned long long p = payload[i];
        int dl = (int)(p >> 32) & 255;
        int slot = atomicAdd(&cur[dl], 1);
        csr[bs + slot] = (int)(unsigned int)p;
    }
}

// ---------------------------------------------------------------------------
// Layer 1 projection into 256-B records:
//   rec[n] bytes [0,128)  : 64 x bf16 features
//   rec[n] bytes [128,160): 8 x fp32 src-alphas, pre-scaled by log2(e)
// ad1 (dst-alphas, also pre-scaled) in a separate small array.
// ---------------------------------------------------------------------------
__global__ void k_h1(const float* __restrict__ x, const float* __restrict__ W1,
                     const float* __restrict__ a_src, const float* __restrict__ a_dst,
                     int N, char* __restrict__ rec, float* __restrict__ ad1) {
    __shared__ float Ws[7 * 64];
    int tid = threadIdx.x;
    for (int i = tid; i < 7 * 64; i += blockDim.x) Ws[i] = W1[i];
    __syncthreads();
    int n = blockIdx.x * 4 + (tid >> 6);
    int lane = tid & 63;
    if (n >= N) return;
    float xv[7];
#pragma unroll
    for (int k = 0; k < 7; ++k) xv[k] = x[n * 7 + k];
    float hv = 0.f;
#pragma unroll
    for (int k = 0; k < 7; ++k) hv += xv[k] * Ws[k * 64 + lane];
    char* rb = rec + ((size_t)n << 8);
    ((unsigned short*)rb)[lane] = f2bf(hv);
    float ps = hv * a_src[lane];
    float pd = hv * a_dst[lane];
#pragma unroll
    for (int off = 1; off < 8; off <<= 1) {
        ps += __shfl_xor(ps, off);
        pd += __shfl_xor(pd, off);
    }
    if ((lane & 7) == 0) {
        ((float*)(rb + 128))[lane >> 3] = ps * L2E;  // exp(x) == exp2(x*L2E)
        ad1[n * 8 + (lane >> 3)] = pd * L2E;
    }
}

// ---------------------------------------------------------------------------
// Layer 1 aggregation + bias + ELU, fused with layer-2 projection (64->2).
// Indices extracted with v_readlane -> SGPR by construction; one scalar
// record base (s<<8) serves both per-edge loads; exp via raw v_exp_f32.
// ---------------------------------------------------------------------------
__global__ void k_agg1(const char* __restrict__ rec, const float* __restrict__ ad1,
                       const int* __restrict__ deg, const int* __restrict__ rows,
                       const int* __restrict__ csr, const float* __restrict__ b1,
                       const float* __restrict__ W2, const float* __restrict__ as2w,
                       const float* __restrict__ ad2w, int N,
                       float4* __restrict__ pack) {
    int n = blockIdx.x * 4 + (threadIdx.x >> 6);
    int lane = threadIdx.x & 63;
    if (n >= N) return;
    n = __builtin_amdgcn_readfirstlane(n);
    int h = lane >> 3;
    int lane2 = lane * 2;            // feat voffset (loop-invariant)
    int aoff = 128 + (h << 2);       // alpha voffset (loop-invariant)
    float adv = ad1[n * 8 + h];
    int d = __builtin_amdgcn_readfirstlane(deg[n]);
    int start = __builtin_amdgcn_readfirstlane(rows[n]);
    float acc = 0.f, den = 0.f;
    int c = 0;
    int nfull = d & ~15;
    for (; c < nfull; c += 16) {
        int idxv = csr[start + c + (lane & 15)];   // 16 indices, wave-broadcast
#pragma unroll
        for (int k = 0; k < 16; ++k) {
            int s = __builtin_amdgcn_readlane(idxv, k);  // SGPR by construction
            const char* rb = rec + ((size_t)(unsigned)s << 8);
            float e = *(const float*)(rb + aoff);
            float f = bf2f(*(const unsigned short*)(rb + lane2));
            float t = e + adv;
            float w = __builtin_amdgcn_exp2f(fmaxf(t, NEG_SLOPE * t));
            den += w;
            acc = fmaf(w, f, acc);
        }
    }
    for (; c < d; ++c) {
        int s = __builtin_amdgcn_readfirstlane(csr[start + c]);
        const char* rb = rec + ((size_t)(unsigned)s << 8);
        float e = *(const float*)(rb + aoff);
        float f = bf2f(*(const unsigned short*)(rb + lane2));
        float t = e + adv;
        float w = __builtin_amdgcn_exp2f(fmaxf(t, NEG_SLOPE * t));
        den += w;
        acc = fmaf(w, f, acc);
    }
    {   // self loop
        const char* rb = rec + ((size_t)n << 8);
        float e = *(const float*)(rb + aoff);
        float f = bf2f(*(const unsigned short*)(rb + lane2));
        float t = e + adv;
        float w = __builtin_amdgcn_exp2f(fmaxf(t, NEG_SLOPE * t));
        den += w;
        acc = fmaf(w, f, acc);
    }
    float o = acc / den + b1[lane];
    float v = o > 0.f ? o : (__expf(o) - 1.f);  // ELU
    float p0 = v * W2[lane * 2 + 0];
    float p1 = v * W2[lane * 2 + 1];
#pragma unroll
    for (int off = 1; off < 64; off <<= 1) {
        p0 += __shfl_xor(p0, off);
        p1 += __shfl_xor(p1, off);
    }
    if (lane == 0) {
        float4 pk;
        pk.x = p0;
        pk.y = p1;
        pk.z = (p0 * as2w[0] + p1 * as2w[1]) * L2E;
        pk.w = (p0 * ad2w[0] + p1 * ad2w[1]) * L2E;
        pack[n] = pk;
    }
}

// ---------------------------------------------------------------------------
// Layer 2 aggregation + bias + log_softmax: single float4 gather per edge.
// ---------------------------------------------------------------------------
__global__ void k_agg2(const float4* __restrict__ pack, const int* __restrict__ deg,
                       const int* __restrict__ rows, const int* __restrict__ csr,
                       const float* __restrict__ b2, int N, float* __restrict__ out) {
    int n = blockIdx.x * 4 + (threadIdx.x >> 6);
    int lane = threadIdx.x & 63;
    if (n >= N) return;
    n = __builtin_amdgcn_readfirstlane(n);
    float4 self = pack[n];
    float adv = self.w;
    int d = __builtin_amdgcn_readfirstlane(deg[n]);
    int start = __builtin_amdgcn_readfirstlane(rows[n]);
    float den = 0.f, a0 = 0.f, a1 = 0.f;
    for (int i = lane; i < d; i += 64) {
        int src = csr[start + i];
        float4 q = pack[src];
        float t = q.z + adv;
        float w = __builtin_amdgcn_exp2f(fmaxf(t, NEG_SLOPE * t));
        den += w;
        a0 += w * q.x;
        a1 += w * q.y;
    }
#pragma unroll
    for (int off = 1; off < 64; off <<= 1) {
        den += __shfl_xor(den, off);
        a0  += __shfl_xor(a0, off);
        a1  += __shfl_xor(a1, off);
    }
    if (lane == 0) {
        float t = self.z + adv;                      // self loop
        float w = __builtin_amdgcn_exp2f(fmaxf(t, NEG_SLOPE * t));
        den += w;
        a0 += w * self.x;
        a1 += w * self.y;
        float o0 = a0 / den + b2[0];
        float o1 = a1 / den + b2[1];
        float m = fmaxf(o0, o1);
        float lse = m + logf(__expf(o0 - m) + __expf(o1 - m));
        out[n * 2 + 0] = o0 - lse;
        out[n * 2 + 1] = o1 - lse;
    }
}

// ---------------------------------------------------------------------------
extern "C" void kernel_launch(void* const* d_in, const int* in_sizes, int n_in,
                              void* d_out, int out_size, void* d_ws, size_t ws_size,
                              hipStream_t stream) {
    const float* x     = (const float*)d_in[0];
    const int*   ei    = (const int*)d_in[1];
    const float* W1    = (const float*)d_in[2];
    const float* as1w  = (const float*)d_in[3];
    const float* ad1w  = (const float*)d_in[4];
    const float* b1    = (const float*)d_in[5];
    const float* W2    = (const float*)d_in[6];
    const float* as2w  = (const float*)d_in[7];
    const float* ad2w  = (const float*)d_in[8];
    const float* b2    = (const float*)d_in[9];
    float* out = (float*)d_out;

    const int N = in_sizes[0] / 7;
    const int E = in_sizes[1] / 2;
    const int* srcA = ei;
    const int* dstA = ei + E;
    const int NB = (N + ((1 << NPB_SHIFT) - 1)) >> NPB_SHIFT;

    size_t off = 0;
    auto alloc = [&](size_t bytes) -> void* {
        void* p = (char*)d_ws + off;
        off += (bytes + 255) & ~(size_t)255;
        return p;
    };
    // payload (8B/edge) is dead after k_buildcsr; rec (256B/node) aliases it.
    size_t payload_bytes = (size_t)E * 8;
    size_t rec_bytes = (size_t)N * 256;
    unsigned long long* payload =
        (unsigned long long*)alloc(payload_bytes > rec_bytes ? payload_bytes : rec_bytes);
    char* rec = (char*)payload;
    float* ad1  = (float*)alloc((size_t)N * 8 * 4);
    float4* pack = (float4*)alloc((size_t)N * 16);
    int*   deg  = (int*)alloc((size_t)N * 4);
    int*   rows = (int*)alloc((size_t)N * 4);
    int*   csr  = (int*)alloc((size_t)E * 4);
    int*   gcount       = (int*)alloc(NBMAX * 4);
    int*   bucket_start = (int*)alloc((NBMAX + 1) * 4);
    int*   cursor_g     = (int*)alloc(NBMAX * 4);

    hipMemsetAsync(gcount, 0, NBMAX * 4, stream);

    const int nb = (N + 3) / 4;
    const int sb = (E + SC_EDGES - 1) / SC_EDGES;

    k_hist<<<1024, 256, 0, stream>>>(dstA, E, NB, gcount);
    k_bscan<<<1, NBMAX, 0, stream>>>(gcount, NB, bucket_start, cursor_g);
    k_scatter<<<sb, 256, 0, stream>>>(srcA, dstA, E, NB, cursor_g, payload);
    k_buildcsr<<<NB, 256, 0, stream>>>(payload, bucket_start, N, deg, rows, csr);

    k_h1<<<nb, 256, 0, stream>>>(x, W1, as1w, ad1w, N, rec, ad1);
    k_agg1<<<nb, 256, 0, stream>>>(rec, ad1, deg, rows, csr, b1,
                                   W2, as2w, ad2w, N, pack);
    k_agg2<<<nb, 256, 0, stream>>>(pack, deg, rows, csr, b2, N, out);
}